// Round 8
// baseline (150.104 us; speedup 1.0000x reference)
//
#include <hip/hip_runtime.h>
#include <hip/hip_fp16.h>
#include <math.h>

constexpr int IN_C = 128, HID_C = 64, OUT_C = 16;
constexpr int BSH = 7;       // bucket = 128 consecutive dst nodes
constexpr int BCAP = 2560;   // bucket capacity (mean 2046, +11 sigma)
constexpr int REC_PT = BCAP / 256;  // 10 records max per thread in k_buck2
constexpr int TILE = 4096;   // edges per tile (256 thr x 16)
constexpr float WSC = 33554432.0f;  // 2^25 fixed-point scale for w in [0,1) (rec; feeds dinv)
// packed pairs: [src:17 | wq:15], w = wq / 32768. N <= 131072, E <= 2.09M
constexpr float WINV15 = 1.0f / 32768.0f;
// packed histG: [in-tile offset:13 | count:13]

using f16x8 = __attribute__((ext_vector_type(8))) _Float16;
using f16x4 = __attribute__((ext_vector_type(4))) _Float16;
using f32x4 = __attribute__((ext_vector_type(4))) float;

// Tile pass with per-wave sub-histograms (round-7 form, marginally best).
__global__ __launch_bounds__(256) void k_tile(const int* __restrict__ row, const int* __restrict__ col,
                                              const float* __restrict__ w, int* __restrict__ histG,
                                              uint2* __restrict__ rec, int E, int nb) {
  __shared__ int hc[4][1024];  // 16 KiB: per-wave counts -> per-wave slot bases
  __shared__ int cs[256];
  int t = threadIdx.x, tile = blockIdx.x;
  int wv = t >> 6;
  for (int i = t; i < 4096; i += 256) ((int*)hc)[i] = 0;
  __syncthreads();
  int base = tile * TILE;
  int colv[TILE / 256];  // register-cache col (avoid re-read in placement)
#pragma unroll
  for (int u = 0; u < TILE / 256; ++u) {
    int e = base + u * 256 + t;
    colv[u] = (e < E) ? col[e] : -1;
    if (e < E) atomicAdd(&hc[wv][colv[u] >> BSH], 1);  // own wave's row only
  }
  __syncthreads();
  // bucket totals (4 per thread) + coarse Hillis-Steele scan over 256 threads
  int tot[4], c0 = 0;
#pragma unroll
  for (int q = 0; q < 4; ++q) {
    int b = 4 * t + q;
    tot[q] = hc[0][b] + hc[1][b] + hc[2][b] + hc[3][b];
    c0 += tot[q];
  }
  cs[t] = c0;
  __syncthreads();
  for (int off = 1; off < 256; off <<= 1) {
    int v = (t >= off) ? cs[t - off] : 0;
    __syncthreads();
    cs[t] += v;
    __syncthreads();
  }
  int r0 = cs[t] - c0;  // exclusive tile-offset of bucket 4t
#pragma unroll
  for (int q = 0; q < 4; ++q) {
    int b = 4 * t + q;
    if (b < nb) histG[(size_t)tile * nb + b] = (r0 << 13) | tot[q];
    int a = r0;          // per-wave slot bases within this bucket's range
    int w0 = hc[0][b], w1 = hc[1][b], w2 = hc[2][b], w3 = hc[3][b];
    hc[0][b] = a; a += w0;
    hc[1][b] = a; a += w1;
    hc[2][b] = a; a += w2;
    hc[3][b] = a;
    r0 += tot[q];
  }
  __syncthreads();
  // placement pass: rank via own wave's counter (no cross-wave collisions)
#pragma unroll
  for (int u = 0; u < TILE / 256; ++u) {
    int e = base + u * 256 + t;
    if (e < E) {
      int r = row[e], d = colv[u];
      int b = d >> BSH;
      unsigned lo = (unsigned)(d & ((1 << BSH) - 1));
      unsigned wf = __float2uint_rn(w[e] * WSC);
      if (wf > 33554431u) wf = 33554431u;
      int slot = atomicAdd(&hc[wv][b], 1);
      rec[(size_t)tile * TILE + slot] = make_uint2((unsigned)r, (lo << 25) | wf);
    }
  }
}

// One block per bucket. NEW: the per-record 9-iteration binary search (record
// index -> tile segment; ~14M dependent LDS reads total) is replaced by direct
// SEGMENT COPY: thread t walks tile-segments t, t+256 and copies each segment's
// ~5.2 records from rec into LDS sq[] at the segment's scan-derived base —
// identical arrival order, zero search. Both phases then read sq (LDS), and
// the rv[] VGPR cache is dropped (-20 VGPRs). Ranks/layout byte-identical.
__global__ __launch_bounds__(256) void k_buck2(const int* __restrict__ histG, const uint2* __restrict__ rec,
                                               unsigned* __restrict__ pairs, int* __restrict__ ptrg,
                                               int* __restrict__ cntg, float* __restrict__ dinvg,
                                               int n, int T, int nb) {
  int b = blockIdx.x, t = threadIdx.x;
  __shared__ int s[512];        // inclusive prefix of per-tile counts for bucket b
  __shared__ int off_s[512];    // in-tile offset of bucket b per tile
  __shared__ uint2 sq[BCAP];    // 20 KiB: bucket records in arrival order
  __shared__ int lcnt[128];
  __shared__ float lws[128];
  __shared__ int lptr[128];
  __shared__ unsigned sp[BCAP]; // 10 KiB staging for coalesced pairs writes
  int i0 = t, i1 = t + 256;
  int v0 = (i0 < T) ? histG[(size_t)i0 * nb + b] : 0;
  int v1 = (i1 < T) ? histG[(size_t)i1 * nb + b] : 0;
  off_s[i0] = v0 >> 13; off_s[i1] = v1 >> 13;
  s[i0] = v0 & 8191; s[i1] = v1 & 8191;
  if (t < 128) { lcnt[t] = 0; lws[t] = 0.f; }
  __syncthreads();
  for (int off = 1; off < 512; off <<= 1) {
    int a0 = (i0 >= off) ? s[i0 - off] : 0;
    int a1 = (i1 >= off) ? s[i1 - off] : 0;
    __syncthreads();
    s[i0] += a0; s[i1] += a1;
    __syncthreads();
  }
  int cnt = s[511];
  if (cnt > BCAP) cnt = BCAP;
  // segment copy: rec -> sq, arrival order (replaces binary search)
  for (int seg = t; seg < T; seg += 256) {
    int e0 = seg ? s[seg - 1] : 0;       // exclusive prefix = dst base in sq
    int c  = s[seg] - e0;                // records of bucket b in this tile
    if (e0 >= BCAP) continue;
    const uint2* rp = rec + (size_t)seg * TILE + off_s[seg];
    for (int q = 0; q < c; ++q) {
      if (e0 + q < BCAP) sq[e0 + q] = rp[q];
    }
  }
  __syncthreads();
  // phase 1: count + weight-sum + rank (from LDS)
  int rk[REC_PT];
#pragma unroll
  for (int u = 0; u < REC_PT; ++u) {
    int i = u * 256 + t;
    if (i < cnt) {
      unsigned m = sq[i].y;
      int lo = m >> 25;
      rk[u] = atomicAdd(&lcnt[lo], 1);
      atomicAdd(&lws[lo], (float)(m & 0x1FFFFFFu) * (1.0f / WSC));
    }
  }
  __syncthreads();
  if (t < 128) lptr[t] = lcnt[t];
  __syncthreads();
  for (int off = 1; off < 128; off <<= 1) {
    int v = (t < 128 && t >= off) ? lptr[t - off] : 0;
    __syncthreads();
    if (t < 128 && t >= off) lptr[t] += v;
    __syncthreads();
  }
  if (t < 128) {
    int d = (b << BSH) + t;
    if (d < n) {
      ptrg[d] = b * BCAP + lptr[t] - lcnt[t];  // exclusive base, capped layout
      cntg[d] = lcnt[t];
      dinvg[d] = rsqrtf(1.0f + lws[t]);        // self-loop weight 1
    }
  }
  // phase 2: emit packed pairs into node-grouped sp
#pragma unroll
  for (int u = 0; u < REC_PT; ++u) {
    int i = u * 256 + t;
    if (i < cnt) {
      uint2 v = sq[i];
      int lo = v.y >> 25;
      unsigned wq = ((v.y & 0x1FFFFFFu) + 512u) >> 10;  // 25b -> 15b round
      if (wq > 32767u) wq = 32767u;
      sp[(lptr[lo] - lcnt[lo]) + rk[u]] = (v.x << 15) | wq;
    }
  }
  __syncthreads();
  for (int i = t; i < cnt; i += 256)           // contiguous 4B/lane stores
    pairs[(size_t)b * BCAP + i] = sp[i];
}

// h1s = dinv * (x @ W1) via MFMA f16 (f32 accumulate), stored fp16.
__global__ __launch_bounds__(256) void k_gemm1(const float* __restrict__ x, const float* __restrict__ W1,
                                               const float* __restrict__ dinv,
                                               __half* __restrict__ h1h, int n) {
  __shared__ _Float16 w1t[HID_C][IN_C];  // 16 KiB, w1t[c][k] = W1[k][c]
  int t = threadIdx.x;
  for (int i = t; i < IN_C * HID_C / 4; i += 256) {
    float4 v = ((const float4*)W1)[i];
    int k = (i * 4) / HID_C;
    int c = (i * 4) % HID_C;
    w1t[c + 0][k] = (_Float16)v.x;
    w1t[c + 1][k] = (_Float16)v.y;
    w1t[c + 2][k] = (_Float16)v.z;
    w1t[c + 3][k] = (_Float16)v.w;
  }
  __syncthreads();
  int wave = t >> 6, lane = t & 63;
  int row0 = (blockIdx.x * 4 + wave) * 16;
  if (row0 >= n) return;
  int lrow = lane & 15, lkg = lane >> 4;  // A row / k-group
  bool rvalid = (row0 + lrow) < n;
  const float* xr = x + (size_t)(row0 + lrow) * IN_C;
  f32x4 acc[4];
#pragma unroll
  for (int cg = 0; cg < 4; ++cg) acc[cg] = (f32x4){0.f, 0.f, 0.f, 0.f};
#pragma unroll
  for (int ks = 0; ks < 4; ++ks) {
    int k0 = ks * 32 + lkg * 8;
    f16x8 a;
    if (rvalid) {
      float4 u0 = *(const float4*)&xr[k0];
      float4 u1 = *(const float4*)&xr[k0 + 4];
      a[0] = (_Float16)u0.x; a[1] = (_Float16)u0.y; a[2] = (_Float16)u0.z; a[3] = (_Float16)u0.w;
      a[4] = (_Float16)u1.x; a[5] = (_Float16)u1.y; a[6] = (_Float16)u1.z; a[7] = (_Float16)u1.w;
    } else {
#pragma unroll
      for (int j = 0; j < 8; ++j) a[j] = (_Float16)0.f;
    }
#pragma unroll
    for (int cg = 0; cg < 4; ++cg) {
      f16x8 bfrag = *(const f16x8*)&w1t[cg * 16 + lrow][k0];
      acc[cg] = __builtin_amdgcn_mfma_f32_16x16x32_f16(a, bfrag, acc[cg], 0, 0, 0);
    }
  }
  float dv[4];
#pragma unroll
  for (int r = 0; r < 4; ++r) {
    int gr = row0 + lkg * 4 + r;
    dv[r] = (gr < n) ? dinv[gr] : 0.f;
  }
#pragma unroll
  for (int cg = 0; cg < 4; ++cg) {
#pragma unroll
    for (int r = 0; r < 4; ++r) {
      int gr = row0 + lkg * 4 + r;
      if (gr < n)
        h1h[(size_t)gr * HID_C + cg * 16 + lrow] = __float2half_rn(dv[r] * acc[cg][r]);
    }
  }
}

// Layer-1 aggregate + FUSED relu + gemm2. 4 edges per gather instruction:
// wave per node; 16 lanes cover one 128B h1h row (half4/lane), 4 slot-groups
// run 4 edges concurrently, 8-deep unroll = 32 edges / 4KB in flight per wave.
// pairs are packed 4B [src:17|wq:15]. CLOSED at the ~3.0 TB/s random-128B-line
// L2-fill wall (rounds 1-7: insensitive to MLP depth, cache hints, stream
// size; +6us from any extra per-edge request; 64B rows pointless at 128B L2
// fill granularity; banding invisible at deg<32-in-flight).
__global__ __launch_bounds__(256) void k_agg1f(const int* __restrict__ ptr, const int* __restrict__ cnt,
                                               const unsigned* __restrict__ pairs, const float* __restrict__ dinv,
                                               const __half* __restrict__ h1h, const float* __restrict__ W2,
                                               __half* __restrict__ h2h, int n) {
  __shared__ float w2s[HID_C * OUT_C];       // 4 KiB
  __shared__ __align__(16) float s[4][68];   // 4 node rows, padded
  int t = threadIdx.x;
  ((float4*)w2s)[t] = ((const float4*)W2)[t];  // 256*16B = 4KB exact
  __syncthreads();                             // w2s ready
  int wv = t >> 6, lane = t & 63;
  int g = lane >> 4;          // edge-slot group 0..3
  int c4 = (lane & 15) * 4;   // channel quad (0,4,...,60)
  int d = blockIdx.x * 4 + wv;
  if (d < n) {
    d = __builtin_amdgcn_readfirstlane(d);  // scalar path for ptr/cnt/dinv
    int k = ptr[d], end = k + cnt[d];
    float dd = dinv[d];
    f32x4 acc = {0.f, 0.f, 0.f, 0.f};
    if (g == 0) {  // self term once (group 0 only)
      f16x4 sv = *(const f16x4*)&h1h[(size_t)d * HID_C + c4];
      acc[0] = (float)sv[0]; acc[1] = (float)sv[1];
      acc[2] = (float)sv[2]; acc[3] = (float)sv[3];
    }
    int last = end - 1;
    for (; k < end; k += 32) {
      unsigned p[8]; float w[8]; f16x4 v[8];
#pragma unroll
      for (int u = 0; u < 8; ++u) {
        int idx = k + u * 4 + g;
        int ic = (idx <= last) ? idx : last;   // branchless tail: clamp index
        p[u] = pairs[ic];                      // 4B, broadcast across 16 lanes
        w[u] = (idx <= last) ? (float)(p[u] & 32767u) * WINV15 : 0.f;
      }
#pragma unroll
      for (int u = 0; u < 8; ++u)              // 32 row-gathers in flight
        v[u] = *(const f16x4*)&h1h[(size_t)(p[u] >> 15) * HID_C + c4];
#pragma unroll
      for (int u = 0; u < 8; ++u) {
        acc[0] = fmaf(w[u], (float)v[u][0], acc[0]);
        acc[1] = fmaf(w[u], (float)v[u][1], acc[1]);
        acc[2] = fmaf(w[u], (float)v[u][2], acc[2]);
        acc[3] = fmaf(w[u], (float)v[u][3], acc[3]);
      }
    }
#pragma unroll
    for (int i = 0; i < 4; ++i) {              // fold 4 slot-groups
      acc[i] += __shfl_xor(acc[i], 16);
      acc[i] += __shfl_xor(acc[i], 32);
    }
    if (g == 0) {
      float4 r;
      r.x = fmaxf(dd * acc[0], 0.f);           // ReLU fused
      r.y = fmaxf(dd * acc[1], 0.f);
      r.z = fmaxf(dd * acc[2], 0.f);
      r.w = fmaxf(dd * acc[3], 0.f);
      *(float4*)&s[wv][c4] = r;
    }
  } else {
    if (g == 0) *(float4*)&s[wv][c4] = make_float4(0.f, 0.f, 0.f, 0.f);
  }
  __syncthreads();
  // fused gemm2: h2s[d][j] = dinv[d] * sum_c agg1[d][c] * W2[c][j]
  if (t < 64) {
    int nl = t >> 4, j = t & 15;
    int dn = blockIdx.x * 4 + nl;
    if (dn < n) {
      float a2 = 0.f;
#pragma unroll
      for (int c = 0; c < HID_C; ++c) a2 = fmaf(s[nl][c], w2s[c * OUT_C + j], a2);
      h2h[(size_t)dn * OUT_C + j] = __float2half_rn(dinv[dn] * a2);
    }
  }
}

// pull-aggregate layer 2 + fused log_softmax. 16 nodes/block, 16 lanes own a
// row (wave-per-node variant regressed ~9us). Packed 4B pairs.
__global__ __launch_bounds__(256) void k_agg2(const int* __restrict__ ptr, const int* __restrict__ cnt,
                                              const unsigned* __restrict__ pairs, const float* __restrict__ dinv,
                                              const __half* __restrict__ h2h, float* __restrict__ out, int n) {
  int t = threadIdx.x;
  int d = blockIdx.x * 16 + (t >> 4);
  if (d >= n) return;
  int j = t & 15;
  int k = ptr[d], end = k + cnt[d];
  float dd = dinv[d];
  float acc = __half2float(h2h[(size_t)d * OUT_C + j]);  // self: h2s[d]
  for (; k + 8 <= end; k += 8) {
    unsigned p[8];
    float v[8];
#pragma unroll
    for (int u = 0; u < 8; ++u) p[u] = pairs[k + u];
#pragma unroll
    for (int u = 0; u < 8; ++u)
      v[u] = __half2float(h2h[(size_t)(p[u] >> 15) * OUT_C + j]);
#pragma unroll
    for (int u = 0; u < 8; ++u) acc = fmaf((float)(p[u] & 32767u) * WINV15, v[u], acc);
  }
  if (k + 4 <= end) {
    unsigned p[4];
    float v[4];
#pragma unroll
    for (int u = 0; u < 4; ++u) p[u] = pairs[k + u];
#pragma unroll
    for (int u = 0; u < 4; ++u)
      v[u] = __half2float(h2h[(size_t)(p[u] >> 15) * OUT_C + j]);
#pragma unroll
    for (int u = 0; u < 4; ++u) acc = fmaf((float)(p[u] & 32767u) * WINV15, v[u], acc);
    k += 4;
  }
  for (; k < end; ++k) {
    unsigned p = pairs[k];
    acc = fmaf((float)(p & 32767u) * WINV15, __half2float(h2h[(size_t)(p >> 15) * OUT_C + j]), acc);
  }
  float lg = dd * acc;
  float mx = lg;
#pragma unroll
  for (int off = 8; off; off >>= 1) mx = fmaxf(mx, __shfl_xor(mx, off, 16));
  float sm = expf(lg - mx);
#pragma unroll
  for (int off = 8; off; off >>= 1) sm += __shfl_xor(sm, off, 16);
  out[(size_t)d * OUT_C + j] = lg - mx - logf(sm);
}

extern "C" void kernel_launch(void* const* d_in, const int* in_sizes, int n_in,
                              void* d_out, int out_size, void* d_ws, size_t ws_size,
                              hipStream_t stream) {
  const float* x  = (const float*)d_in[0];
  const int*   ei = (const int*)d_in[1];
  const float* ew = (const float*)d_in[2];
  const float* W1 = (const float*)d_in[3];
  const float* W2 = (const float*)d_in[4];
  const int N = in_sizes[0] / IN_C;
  const int E = in_sizes[2];
  const int* row = ei;
  const int* col = ei + E;
  float* out = (float*)d_out;
  const int NBUK = (N + (1 << BSH) - 1) >> BSH;   // 782 (<=1024)
  const int T = (E + TILE - 1) / TILE;            // 391 (<=512)

  // ws layout: pairs(4B) | ptr | cnt | dinv | histG | uni(rec / h1h+h2h)
  char* p = (char*)d_ws;
  unsigned* pairs = (unsigned*)p;     p += (size_t)NBUK * BCAP * 4;
  int*   ptr  = (int*)p;              p += (size_t)N * 4;
  int*   cnt  = (int*)p;              p += (size_t)N * 4;
  float* dinv = (float*)p;            p += (size_t)N * 4;
  int*   histG= (int*)p;              p += (size_t)T * NBUK * 4;
  char*  uni  = p;                    p += (size_t)N * HID_C * 4;  // max(rec 12.8MB, h1h 12.8+h2h 3.2MB)
  uint2* rec  = (uint2*)uni;          // tile-major, T*TILE*8; dead before k_gemm1 writes h1h
  __half* h1h = (__half*)uni;
  __half* h2h = (__half*)(uni + (size_t)N * HID_C * 2);  // after h1h

  dim3 b(256);
  k_tile <<<T, b, 0, stream>>>(row, col, ew, histG, rec, E, NBUK);
  k_buck2<<<NBUK, b, 0, stream>>>(histG, rec, pairs, ptr, cnt, dinv, N, T, NBUK);
  k_gemm1<<<(N + 63) / 64, b, 0, stream>>>(x, W1, dinv, h1h, N);
  k_agg1f<<<(N + 3) / 4, b, 0, stream>>>(ptr, cnt, pairs, dinv, h1h, W2, h2h, N);
  k_agg2 <<<(N + 15) / 16, b, 0, stream>>>(ptr, cnt, pairs, dinv, h2h, out, N);
}

// Round 9
// 142.328 us; speedup vs baseline: 1.0546x; 1.0546x over previous
//
#include <hip/hip_runtime.h>
#include <hip/hip_fp16.h>
#include <math.h>

constexpr int IN_C = 128, HID_C = 64, OUT_C = 16;
constexpr int BSH = 7;       // bucket = 128 consecutive dst nodes
constexpr int BCAP = 2560;   // bucket capacity (mean 2046, +11 sigma)
constexpr int REC_PT = BCAP / 256;  // 10 records max per thread in k_buck2
constexpr int TILE = 4096;   // edges per tile (256 thr x 16)
constexpr float WSC = 33554432.0f;  // 2^25 fixed-point scale for w in [0,1) (rec; feeds dinv)
// packed pairs: [src:17 | wq:15], w = wq / 32768. N <= 131072, E <= 2.09M
constexpr float WINV15 = 1.0f / 32768.0f;
// packed histG: [in-tile offset:13 | count:13]

using f16x8 = __attribute__((ext_vector_type(8))) _Float16;
using f16x4 = __attribute__((ext_vector_type(4))) _Float16;
using f32x4 = __attribute__((ext_vector_type(4))) float;

// Tile pass with per-wave sub-histograms (round-7 form, best verified).
__global__ __launch_bounds__(256) void k_tile(const int* __restrict__ row, const int* __restrict__ col,
                                              const float* __restrict__ w, int* __restrict__ histG,
                                              uint2* __restrict__ rec, int E, int nb) {
  __shared__ int hc[4][1024];  // 16 KiB: per-wave counts -> per-wave slot bases
  __shared__ int cs[256];
  int t = threadIdx.x, tile = blockIdx.x;
  int wv = t >> 6;
  for (int i = t; i < 4096; i += 256) ((int*)hc)[i] = 0;
  __syncthreads();
  int base = tile * TILE;
  int colv[TILE / 256];  // register-cache col (avoid re-read in placement)
#pragma unroll
  for (int u = 0; u < TILE / 256; ++u) {
    int e = base + u * 256 + t;
    colv[u] = (e < E) ? col[e] : -1;
    if (e < E) atomicAdd(&hc[wv][colv[u] >> BSH], 1);  // own wave's row only
  }
  __syncthreads();
  // bucket totals (4 per thread) + coarse Hillis-Steele scan over 256 threads
  int tot[4], c0 = 0;
#pragma unroll
  for (int q = 0; q < 4; ++q) {
    int b = 4 * t + q;
    tot[q] = hc[0][b] + hc[1][b] + hc[2][b] + hc[3][b];
    c0 += tot[q];
  }
  cs[t] = c0;
  __syncthreads();
  for (int off = 1; off < 256; off <<= 1) {
    int v = (t >= off) ? cs[t - off] : 0;
    __syncthreads();
    cs[t] += v;
    __syncthreads();
  }
  int r0 = cs[t] - c0;  // exclusive tile-offset of bucket 4t
#pragma unroll
  for (int q = 0; q < 4; ++q) {
    int b = 4 * t + q;
    if (b < nb) histG[(size_t)tile * nb + b] = (r0 << 13) | tot[q];
    int a = r0;          // per-wave slot bases within this bucket's range
    int w0 = hc[0][b], w1 = hc[1][b], w2 = hc[2][b], w3 = hc[3][b];
    hc[0][b] = a; a += w0;
    hc[1][b] = a; a += w1;
    hc[2][b] = a; a += w2;
    hc[3][b] = a;
    r0 += tot[q];
  }
  __syncthreads();
  // placement pass: rank via own wave's counter (no cross-wave collisions)
#pragma unroll
  for (int u = 0; u < TILE / 256; ++u) {
    int e = base + u * 256 + t;
    if (e < E) {
      int r = row[e], d = colv[u];
      int b = d >> BSH;
      unsigned lo = (unsigned)(d & ((1 << BSH) - 1));
      unsigned wf = __float2uint_rn(w[e] * WSC);
      if (wf > 33554431u) wf = 33554431u;
      int slot = atomicAdd(&hc[wv][b], 1);
      rec[(size_t)tile * TILE + slot] = make_uint2((unsigned)r, (lo << 25) | wf);
    }
  }
}

// One block per bucket: scan per-tile counts (from packed histG), binary-search
// gather of the bucket's records from tile-major rec (COALESCED global reads —
// the round-8 segment-copy variant broke coalescing and regressed 7.7us),
// LDS rank by node, emit packed CSR pairs + ptr/cnt/dinv.
__global__ __launch_bounds__(256) void k_buck2(const int* __restrict__ histG, const uint2* __restrict__ rec,
                                               unsigned* __restrict__ pairs, int* __restrict__ ptrg,
                                               int* __restrict__ cntg, float* __restrict__ dinvg,
                                               int n, int T, int nb) {
  int b = blockIdx.x, t = threadIdx.x;
  __shared__ int s[512];      // inclusive prefix of per-tile counts for bucket b
  __shared__ int off_s[512];  // in-tile offset of bucket b per tile
  __shared__ int lcnt[128];
  __shared__ float lws[128];
  __shared__ int lptr[128];
  __shared__ unsigned sp[BCAP];  // 10 KiB staging for coalesced pairs writes
  int i0 = t, i1 = t + 256;
  int v0 = (i0 < T) ? histG[(size_t)i0 * nb + b] : 0;
  int v1 = (i1 < T) ? histG[(size_t)i1 * nb + b] : 0;
  off_s[i0] = v0 >> 13; off_s[i1] = v1 >> 13;
  s[i0] = v0 & 8191; s[i1] = v1 & 8191;
  if (t < 128) { lcnt[t] = 0; lws[t] = 0.f; }
  __syncthreads();
  for (int off = 1; off < 512; off <<= 1) {
    int a0 = (i0 >= off) ? s[i0 - off] : 0;
    int a1 = (i1 >= off) ? s[i1 - off] : 0;
    __syncthreads();
    s[i0] += a0; s[i1] += a1;
    __syncthreads();
  }
  int cnt = s[511];
  if (cnt > BCAP) cnt = BCAP;
  uint2 rv[REC_PT];
  int rk[REC_PT];
#pragma unroll
  for (int u = 0; u < REC_PT; ++u) {
    int i = u * 256 + t;
    if (i < cnt) {
      int lo_ = 0, hi_ = 511;               // first seg with s[seg] > i
      while (lo_ < hi_) { int m = (lo_ + hi_) >> 1; if (s[m] > i) hi_ = m; else lo_ = m + 1; }
      int seg = lo_;
      int ex = seg ? s[seg - 1] : 0;        // exclusive prefix of seg
      uint2 v = rec[(size_t)seg * TILE + off_s[seg] + (i - ex)];
      rv[u] = v;
      int lo = v.y >> 25;
      rk[u] = atomicAdd(&lcnt[lo], 1);
      atomicAdd(&lws[lo], (float)(v.y & 0x1FFFFFFu) * (1.0f / WSC));
    }
  }
  __syncthreads();
  if (t < 128) lptr[t] = lcnt[t];
  __syncthreads();
  for (int off = 1; off < 128; off <<= 1) {
    int v = (t < 128 && t >= off) ? lptr[t - off] : 0;
    __syncthreads();
    if (t < 128 && t >= off) lptr[t] += v;
    __syncthreads();
  }
  if (t < 128) {
    int d = (b << BSH) + t;
    if (d < n) {
      ptrg[d] = b * BCAP + lptr[t] - lcnt[t];  // exclusive base, capped layout
      cntg[d] = lcnt[t];
      dinvg[d] = rsqrtf(1.0f + lws[t]);        // self-loop weight 1
    }
  }
#pragma unroll
  for (int u = 0; u < REC_PT; ++u) {
    int i = u * 256 + t;
    if (i < cnt) {
      uint2 v = rv[u];
      int lo = v.y >> 25;
      unsigned wq = ((v.y & 0x1FFFFFFu) + 512u) >> 10;  // 25b -> 15b round
      if (wq > 32767u) wq = 32767u;
      sp[(lptr[lo] - lcnt[lo]) + rk[u]] = (v.x << 15) | wq;
    }
  }
  __syncthreads();
  for (int i = t; i < cnt; i += 256)           // contiguous 4B/lane stores
    pairs[(size_t)b * BCAP + i] = sp[i];
}

// h1s = dinv * (x @ W1) via MFMA f16 (f32 accumulate), stored fp16.
__global__ __launch_bounds__(256) void k_gemm1(const float* __restrict__ x, const float* __restrict__ W1,
                                               const float* __restrict__ dinv,
                                               __half* __restrict__ h1h, int n) {
  __shared__ _Float16 w1t[HID_C][IN_C];  // 16 KiB, w1t[c][k] = W1[k][c]
  int t = threadIdx.x;
  for (int i = t; i < IN_C * HID_C / 4; i += 256) {
    float4 v = ((const float4*)W1)[i];
    int k = (i * 4) / HID_C;
    int c = (i * 4) % HID_C;
    w1t[c + 0][k] = (_Float16)v.x;
    w1t[c + 1][k] = (_Float16)v.y;
    w1t[c + 2][k] = (_Float16)v.z;
    w1t[c + 3][k] = (_Float16)v.w;
  }
  __syncthreads();
  int wave = t >> 6, lane = t & 63;
  int row0 = (blockIdx.x * 4 + wave) * 16;
  if (row0 >= n) return;
  int lrow = lane & 15, lkg = lane >> 4;  // A row / k-group
  bool rvalid = (row0 + lrow) < n;
  const float* xr = x + (size_t)(row0 + lrow) * IN_C;
  f32x4 acc[4];
#pragma unroll
  for (int cg = 0; cg < 4; ++cg) acc[cg] = (f32x4){0.f, 0.f, 0.f, 0.f};
#pragma unroll
  for (int ks = 0; ks < 4; ++ks) {
    int k0 = ks * 32 + lkg * 8;
    f16x8 a;
    if (rvalid) {
      float4 u0 = *(const float4*)&xr[k0];
      float4 u1 = *(const float4*)&xr[k0 + 4];
      a[0] = (_Float16)u0.x; a[1] = (_Float16)u0.y; a[2] = (_Float16)u0.z; a[3] = (_Float16)u0.w;
      a[4] = (_Float16)u1.x; a[5] = (_Float16)u1.y; a[6] = (_Float16)u1.z; a[7] = (_Float16)u1.w;
    } else {
#pragma unroll
      for (int j = 0; j < 8; ++j) a[j] = (_Float16)0.f;
    }
#pragma unroll
    for (int cg = 0; cg < 4; ++cg) {
      f16x8 bfrag = *(const f16x8*)&w1t[cg * 16 + lrow][k0];
      acc[cg] = __builtin_amdgcn_mfma_f32_16x16x32_f16(a, bfrag, acc[cg], 0, 0, 0);
    }
  }
  float dv[4];
#pragma unroll
  for (int r = 0; r < 4; ++r) {
    int gr = row0 + lkg * 4 + r;
    dv[r] = (gr < n) ? dinv[gr] : 0.f;
  }
#pragma unroll
  for (int cg = 0; cg < 4; ++cg) {
#pragma unroll
    for (int r = 0; r < 4; ++r) {
      int gr = row0 + lkg * 4 + r;
      if (gr < n)
        h1h[(size_t)gr * HID_C + cg * 16 + lrow] = __float2half_rn(dv[r] * acc[cg][r]);
    }
  }
}

// Layer-1 aggregate + FUSED relu + gemm2. 4 edges per gather instruction:
// wave per node; 16 lanes cover one 128B h1h row (half4/lane), 4 slot-groups
// run 4 edges concurrently, 8-deep unroll = 32 edges / 4KB in flight per wave.
// pairs are packed 4B [src:17|wq:15]. CLOSED at the ~3.0 TB/s random-128B-line
// L2-fill wall (rounds 1-7: insensitive to MLP depth, cache hints, stream
// size; +6us from any extra per-edge request; 64B rows pointless at 128B L2
// fill granularity; banding invisible at deg<32-in-flight).
__global__ __launch_bounds__(256) void k_agg1f(const int* __restrict__ ptr, const int* __restrict__ cnt,
                                               const unsigned* __restrict__ pairs, const float* __restrict__ dinv,
                                               const __half* __restrict__ h1h, const float* __restrict__ W2,
                                               __half* __restrict__ h2h, int n) {
  __shared__ float w2s[HID_C * OUT_C];       // 4 KiB
  __shared__ __align__(16) float s[4][68];   // 4 node rows, padded
  int t = threadIdx.x;
  ((float4*)w2s)[t] = ((const float4*)W2)[t];  // 256*16B = 4KB exact
  __syncthreads();                             // w2s ready
  int wv = t >> 6, lane = t & 63;
  int g = lane >> 4;          // edge-slot group 0..3
  int c4 = (lane & 15) * 4;   // channel quad (0,4,...,60)
  int d = blockIdx.x * 4 + wv;
  if (d < n) {
    d = __builtin_amdgcn_readfirstlane(d);  // scalar path for ptr/cnt/dinv
    int k = ptr[d], end = k + cnt[d];
    float dd = dinv[d];
    f32x4 acc = {0.f, 0.f, 0.f, 0.f};
    if (g == 0) {  // self term once (group 0 only)
      f16x4 sv = *(const f16x4*)&h1h[(size_t)d * HID_C + c4];
      acc[0] = (float)sv[0]; acc[1] = (float)sv[1];
      acc[2] = (float)sv[2]; acc[3] = (float)sv[3];
    }
    int last = end - 1;
    for (; k < end; k += 32) {
      unsigned p[8]; float w[8]; f16x4 v[8];
#pragma unroll
      for (int u = 0; u < 8; ++u) {
        int idx = k + u * 4 + g;
        int ic = (idx <= last) ? idx : last;   // branchless tail: clamp index
        p[u] = pairs[ic];                      // 4B, broadcast across 16 lanes
        w[u] = (idx <= last) ? (float)(p[u] & 32767u) * WINV15 : 0.f;
      }
#pragma unroll
      for (int u = 0; u < 8; ++u)              // 32 row-gathers in flight
        v[u] = *(const f16x4*)&h1h[(size_t)(p[u] >> 15) * HID_C + c4];
#pragma unroll
      for (int u = 0; u < 8; ++u) {
        acc[0] = fmaf(w[u], (float)v[u][0], acc[0]);
        acc[1] = fmaf(w[u], (float)v[u][1], acc[1]);
        acc[2] = fmaf(w[u], (float)v[u][2], acc[2]);
        acc[3] = fmaf(w[u], (float)v[u][3], acc[3]);
      }
    }
#pragma unroll
    for (int i = 0; i < 4; ++i) {              // fold 4 slot-groups
      acc[i] += __shfl_xor(acc[i], 16);
      acc[i] += __shfl_xor(acc[i], 32);
    }
    if (g == 0) {
      float4 r;
      r.x = fmaxf(dd * acc[0], 0.f);           // ReLU fused
      r.y = fmaxf(dd * acc[1], 0.f);
      r.z = fmaxf(dd * acc[2], 0.f);
      r.w = fmaxf(dd * acc[3], 0.f);
      *(float4*)&s[wv][c4] = r;
    }
  } else {
    if (g == 0) *(float4*)&s[wv][c4] = make_float4(0.f, 0.f, 0.f, 0.f);
  }
  __syncthreads();
  // fused gemm2: h2s[d][j] = dinv[d] * sum_c agg1[d][c] * W2[c][j]
  if (t < 64) {
    int nl = t >> 4, j = t & 15;
    int dn = blockIdx.x * 4 + nl;
    if (dn < n) {
      float a2 = 0.f;
#pragma unroll
      for (int c = 0; c < HID_C; ++c) a2 = fmaf(s[nl][c], w2s[c * OUT_C + j], a2);
      h2h[(size_t)dn * OUT_C + j] = __float2half_rn(dinv[dn] * a2);
    }
  }
}

// pull-aggregate layer 2 + fused log_softmax. 16 nodes/block, 16 lanes own a
// row (wave-per-node variant regressed ~9us). Packed 4B pairs.
__global__ __launch_bounds__(256) void k_agg2(const int* __restrict__ ptr, const int* __restrict__ cnt,
                                              const unsigned* __restrict__ pairs, const float* __restrict__ dinv,
                                              const __half* __restrict__ h2h, float* __restrict__ out, int n) {
  int t = threadIdx.x;
  int d = blockIdx.x * 16 + (t >> 4);
  if (d >= n) return;
  int j = t & 15;
  int k = ptr[d], end = k + cnt[d];
  float dd = dinv[d];
  float acc = __half2float(h2h[(size_t)d * OUT_C + j]);  // self: h2s[d]
  for (; k + 8 <= end; k += 8) {
    unsigned p[8];
    float v[8];
#pragma unroll
    for (int u = 0; u < 8; ++u) p[u] = pairs[k + u];
#pragma unroll
    for (int u = 0; u < 8; ++u)
      v[u] = __half2float(h2h[(size_t)(p[u] >> 15) * OUT_C + j]);
#pragma unroll
    for (int u = 0; u < 8; ++u) acc = fmaf((float)(p[u] & 32767u) * WINV15, v[u], acc);
  }
  if (k + 4 <= end) {
    unsigned p[4];
    float v[4];
#pragma unroll
    for (int u = 0; u < 4; ++u) p[u] = pairs[k + u];
#pragma unroll
    for (int u = 0; u < 4; ++u)
      v[u] = __half2float(h2h[(size_t)(p[u] >> 15) * OUT_C + j]);
#pragma unroll
    for (int u = 0; u < 4; ++u) acc = fmaf((float)(p[u] & 32767u) * WINV15, v[u], acc);
    k += 4;
  }
  for (; k < end; ++k) {
    unsigned p = pairs[k];
    acc = fmaf((float)(p & 32767u) * WINV15, __half2float(h2h[(size_t)(p >> 15) * OUT_C + j]), acc);
  }
  float lg = dd * acc;
  float mx = lg;
#pragma unroll
  for (int off = 8; off; off >>= 1) mx = fmaxf(mx, __shfl_xor(mx, off, 16));
  float sm = expf(lg - mx);
#pragma unroll
  for (int off = 8; off; off >>= 1) sm += __shfl_xor(sm, off, 16);
  out[(size_t)d * OUT_C + j] = lg - mx - logf(sm);
}

extern "C" void kernel_launch(void* const* d_in, const int* in_sizes, int n_in,
                              void* d_out, int out_size, void* d_ws, size_t ws_size,
                              hipStream_t stream) {
  const float* x  = (const float*)d_in[0];
  const int*   ei = (const int*)d_in[1];
  const float* ew = (const float*)d_in[2];
  const float* W1 = (const float*)d_in[3];
  const float* W2 = (const float*)d_in[4];
  const int N = in_sizes[0] / IN_C;
  const int E = in_sizes[2];
  const int* row = ei;
  const int* col = ei + E;
  float* out = (float*)d_out;
  const int NBUK = (N + (1 << BSH) - 1) >> BSH;   // 782 (<=1024)
  const int T = (E + TILE - 1) / TILE;            // 391 (<=512)

  // ws layout: pairs(4B) | ptr | cnt | dinv | histG | uni(rec / h1h+h2h)
  char* p = (char*)d_ws;
  unsigned* pairs = (unsigned*)p;     p += (size_t)NBUK * BCAP * 4;
  int*   ptr  = (int*)p;              p += (size_t)N * 4;
  int*   cnt  = (int*)p;              p += (size_t)N * 4;
  float* dinv = (float*)p;            p += (size_t)N * 4;
  int*   histG= (int*)p;              p += (size_t)T * NBUK * 4;
  char*  uni  = p;                    p += (size_t)N * HID_C * 4;  // max(rec 12.8MB, h1h 12.8+h2h 3.2MB)
  uint2* rec  = (uint2*)uni;          // tile-major, T*TILE*8; dead before k_gemm1 writes h1h
  __half* h1h = (__half*)uni;
  __half* h2h = (__half*)(uni + (size_t)N * HID_C * 2);  // after h1h

  dim3 b(256);
  k_tile <<<T, b, 0, stream>>>(row, col, ew, histG, rec, E, NBUK);
  k_buck2<<<NBUK, b, 0, stream>>>(histG, rec, pairs, ptr, cnt, dinv, N, T, NBUK);
  k_gemm1<<<(N + 63) / 64, b, 0, stream>>>(x, W1, dinv, h1h, N);
  k_agg1f<<<(N + 3) / 4, b, 0, stream>>>(ptr, cnt, pairs, dinv, h1h, W2, h2h, N);
  k_agg2 <<<(N + 15) / 16, b, 0, stream>>>(ptr, cnt, pairs, dinv, h2h, out, N);
}